// Round 9
// baseline (2394.842 us; speedup 1.0000x reference)
//
#include <hip/hip_runtime.h>
#include <hip/hip_bf16.h>

// NoisyActLin: y = fakequant(x) @ fakequant(W).T + bias
// x: [4,2048,2048] f32 -> M=8192, K=2048 ; W: [8192,2048] f32 -> N=8192
// out: [8192, 8192] f32
//
// GEMM: 256x256 tile, BK=32, 8 waves (2Mx4N), per-wave 128x64.
// KEY CHANGE (r8 post-mortem): 64KB LDS (BK=32 dbuf) -> 2 blocks/CU.
// Cross-block wave overlap (m114) hides the LDS-read port time under the
// other block's MFMA; intra-block pipelining attempts (r3/r7/r8) all failed
// because 1-block/CU lockstep serializes reads+MFMA.
// Wait discipline (r6/r8 lesson): every lands-guarantee = vm-wait BEFORE a
// barrier. Phase: stage-next -> 12 ds_reads -> lgkm(0) -> 32 MFMA -> vmcnt(0)
// -> barrier. R2-verified 64B-row swizzle (byte bit5 ^= bit9), 0 conflicts.

using f16x8 = __attribute__((ext_vector_type(8))) _Float16;
using f32x4 = __attribute__((ext_vector_type(4))) float;

#define AS1 __attribute__((address_space(1)))
#define AS3 __attribute__((address_space(3)))

static __device__ __forceinline__ void gload_lds16(const void* g, void* l) {
    __builtin_amdgcn_global_load_lds((const AS1 void*)g, (AS3 void*)l, 16, 0, 0);
}

// ---------------- weight fake-quant: one block per row ----------------
__global__ __launch_bounds__(256) void wquant_kernel(
    const float* __restrict__ W, const float* __restrict__ lws,
    _Float16* __restrict__ Wq) {
    constexpr int K = 2048;
    const int row = blockIdx.x;
    const int t = threadIdx.x;
    const float* w = W + (size_t)row * K;

    float4 v0 = ((const float4*)w)[t * 2];
    float4 v1 = ((const float4*)w)[t * 2 + 1];
    float vals[8] = {v0.x, v0.y, v0.z, v0.w, v1.x, v1.y, v1.z, v1.w};

    float mn = vals[0], mx = vals[0];
#pragma unroll
    for (int i = 1; i < 8; ++i) {
        mn = fminf(mn, vals[i]);
        mx = fmaxf(mx, vals[i]);
    }
#pragma unroll
    for (int off = 32; off >= 1; off >>= 1) {
        mn = fminf(mn, __shfl_xor(mn, off));
        mx = fmaxf(mx, __shfl_xor(mx, off));
    }
    __shared__ float smn[4], smx[4];
    if ((t & 63) == 0) { smn[t >> 6] = mn; smx[t >> 6] = mx; }
    __syncthreads();
    mn = fminf(fminf(smn[0], smn[1]), fminf(smn[2], smn[3]));
    mx = fmaxf(fmaxf(smx[0], smx[1]), fmaxf(smx[2], smx[3]));

    const float l = lws[row];
    const float ws = exp2f(l);     // power of two -> exact
    const float rs = exp2f(-l);    // exact reciprocal
    const float qwmin = rintf(mn * rs * 2.0f) * 0.5f * ws;
    const float qwmax = rintf(mx * rs * 2.0f) * 0.5f * ws;

    f16x8 out;
#pragma unroll
    for (int i = 0; i < 8; ++i) {
        float c = fminf(fmaxf(vals[i], qwmin), qwmax);
        float qw = rintf((c - qwmin) * rs);
        out[i] = (_Float16)(qw * ws + qwmin);
    }
    *(f16x8*)&Wq[(size_t)row * K + (size_t)t * 8] = out;
}

// ---------------- activation fake-quant: elementwise ----------------
__global__ __launch_bounds__(256) void xquant_kernel(
    const float* __restrict__ X,
    const float* __restrict__ las, const float* __restrict__ laq,
    const float* __restrict__ ab, _Float16* __restrict__ Xq) {
    const float ls = las[0], lq = laq[0];
    const float s = exp2f(ls);
    const float rs = exp2f(-ls);
    const float q = exp2f(lq);
    const float zp = rintf(ab[0] * rs * 2.0f) * 0.5f * s;
    const float lo = zp;
    const float hi = (zp + q) - s;

    const size_t base = ((size_t)blockIdx.x * 256 + threadIdx.x) * 8;
    float4 v0 = *(const float4*)&X[base];
    float4 v1 = *(const float4*)&X[base + 4];
    float vals[8] = {v0.x, v0.y, v0.z, v0.w, v1.x, v1.y, v1.z, v1.w};

    f16x8 out;
#pragma unroll
    for (int i = 0; i < 8; ++i) {
        float c = fminf(fmaxf(vals[i], lo), hi);
        float qx = rintf((c - zp) * rs);
        out[i] = (_Float16)(qx * s + zp);
    }
    *(f16x8*)&Xq[base] = out;
}

// ---------------- GEMM: C[M][N] = A[M][K] * B[N][K]^T + bias ----------------
// LDS 64KB: A [db2][256 rows][32 k] f16 (2x16KB at 0), B same at +32768.
// Phase kt (db=kt&1), 64 phases:
//   STAGET(db^1, kt+1)   4 loads   (WAR: db^1's readers drained at phase
//                                   kt-1's LGKM0, before its barrier)
//   12 ds_read_b128 (tile kt from db)
//   LGKM(0)+sched_barrier ; setprio(1) ; 32 MFMA ; setprio(0)
//   VMC(0) ; BAR          (landing: my 4 loads drained BEFORE the barrier;
//                          after barrier ALL waves' loads landed -> next
//                          phase's reads safe. r6/r8 rule.)
__global__ __launch_bounds__(512, 4) void gemm_kernel(
    const _Float16* __restrict__ A, const _Float16* __restrict__ B,
    const float* __restrict__ bias, float* __restrict__ C) {
    constexpr int N = 8192, K = 2048;
    constexpr int KT = K / 32;          // 64 K-steps
    constexpr int NBN = N / 256;        // 32

    __shared__ char smem[65536];        // A: 0..32K (2 bufs), B: 32K..64K

    // XCD-aware swizzle (nwg = 1024, %8 == 0 -> bijective)
    const int bid = blockIdx.x;
    const int cpx = gridDim.x >> 3;
    const int swzb = (bid & 7) * cpx + (bid >> 3);
    const int bm = swzb / NBN;
    const int bn = swzb % NBN;

    const int t = threadIdx.x;
    const int lane = t & 63;
    const int wid = t >> 6;
    const int wr = wid >> 2;            // 0..1 (M half)
    const int wc = wid & 3;             // 0..3 (N quarter)
    const int l15 = lane & 15;
    const int lq = lane >> 4;

    // staging: tile [256 rows][32 k] f16 = 16384 B, 64B rows, linear LDS dest,
    // pre-swizzled global source (swizzle: byte bit5 ^= bit9; bit9 = row bit3).
    // R2/R3-verified: 0 bank conflicts.
    const int d0 = t * 16, d1 = d0 + 8192;
    const int r0 = d0 >> 6, c0 = (((d0 & 63) ^ (((d0 >> 9) & 1) << 5)) >> 1);
    const int r1 = d1 >> 6, c1 = (((d1 & 63) ^ (((d1 >> 9) & 1) << 5)) >> 1);
    const _Float16* Agb = A + (size_t)bm * 256 * K;
    const _Float16* Bgb = B + (size_t)bn * 256 * K;

    // read-side swizzled k-col byte offset (row bit3 == l15 bit3)
    const int cp = (lq * 16) ^ ((l15 & 8) << 2);

    f32x4 acc[8][4] = {};
    f16x8 fA[8], fB[4];

#define STAGET(DBS, KS) do {                                                   \
        const _Float16* _ga = Agb + (size_t)(KS) * 32;                         \
        char* _la = smem + (DBS) * 16384;                                      \
        gload_lds16(_ga + (size_t)r0 * K + c0, _la + d0);                      \
        gload_lds16(_ga + (size_t)r1 * K + c1, _la + d1);                      \
        const _Float16* _gb = Bgb + (size_t)(KS) * 32;                         \
        char* _lb = smem + 32768 + (DBS) * 16384;                              \
        gload_lds16(_gb + (size_t)r0 * K + c0, _lb + d0);                      \
        gload_lds16(_gb + (size_t)r1 * K + c1, _lb + d1);                      \
    } while (0)

#define VMC(NN) asm volatile("s_waitcnt vmcnt(" #NN ")" ::: "memory")
#define BAR()   __builtin_amdgcn_s_barrier()
#define PRIO(P) __builtin_amdgcn_s_setprio(P)

    // ---- prologue: stage tile 0 into db0; wait BEFORE barrier ----
    STAGET(0, 0);
    VMC(0);
    BAR();

    for (int kt = 0; kt < KT; ++kt) {
        const int db = kt & 1;
        const int nx = (kt + 1 < KT) ? kt + 1 : KT - 1;

        STAGET(db ^ 1, nx);              // 4 loads for tile kt+1

        // 12 ds_read_b128: fragments of tile kt
        {
            const char* _a = smem + db * 16384 + (wr * 128 + l15) * 64 + cp;
#pragma unroll
            for (int m = 0; m < 8; ++m)
                fA[m] = *(const f16x8*)(_a + m * 1024);
            const char* _b = smem + 32768 + db * 16384 +
                             (wc * 64 + l15) * 64 + cp;
#pragma unroll
            for (int n = 0; n < 4; ++n)
                fB[n] = *(const f16x8*)(_b + n * 1024);
        }
        asm volatile("s_waitcnt lgkmcnt(0)" ::: "memory");
        __builtin_amdgcn_sched_barrier(0);

        PRIO(1);
#pragma unroll
        for (int m = 0; m < 8; ++m)
#pragma unroll
            for (int n = 0; n < 4; ++n)
                acc[m][n] = __builtin_amdgcn_mfma_f32_16x16x32_f16(
                    fA[m], fB[n], acc[m][n], 0, 0, 0);
        PRIO(0);

        VMC(0);                          // my 4 loads landed (BEFORE barrier)
        BAR();                           // => all waves' loads landed
    }
#undef STAGET
#undef VMC
#undef BAR
#undef PRIO

    // ---- epilogue: C/D mapping col=lane&15, row=(lane>>4)*4+reg ----
#pragma unroll
    for (int m = 0; m < 8; ++m) {
        const int row = bm * 256 + wr * 128 + m * 16 + lq * 4;
#pragma unroll
        for (int n = 0; n < 4; ++n) {
            const int col = bn * 256 + wc * 64 + n * 16 + l15;
            const float bv = bias[col];
#pragma unroll
            for (int r = 0; r < 4; ++r) {
                C[(size_t)(row + r) * N + col] = acc[m][n][r] + bv;
            }
        }
    }
}

extern "C" void kernel_launch(void* const* d_in, const int* in_sizes, int n_in,
                              void* d_out, int out_size, void* d_ws, size_t ws_size,
                              hipStream_t stream) {
    const float* x    = (const float*)d_in[0];   // [4,2048,2048]
    const float* w    = (const float*)d_in[1];   // [8192,2048]
    const float* bias = (const float*)d_in[2];   // [8192]
    const float* las  = (const float*)d_in[3];   // log_act_s [1]
    const float* laq  = (const float*)d_in[4];   // log_act_q [1]
    const float* ab   = (const float*)d_in[5];   // act_b [1]
    const float* lws  = (const float*)d_in[6];   // log_wght_s [8192]
    float* out = (float*)d_out;

    constexpr size_t MK = (size_t)8192 * 2048;
    _Float16* xq = (_Float16*)d_ws;
    _Float16* wq = (_Float16*)((char*)d_ws + MK * sizeof(_Float16));

    xquant_kernel<<<8192, 256, 0, stream>>>(x, las, laq, ab, xq);
    wquant_kernel<<<8192, 256, 0, stream>>>(w, lws, wq);
    gemm_kernel<<<1024, 512, 0, stream>>>(xq, wq, bias, out);
}

// Round 10
// 304.889 us; speedup vs baseline: 7.8548x; 7.8548x over previous
//
#include <hip/hip_runtime.h>
#include <hip/hip_bf16.h>

// NoisyActLin: y = fakequant(x) @ fakequant(W).T + bias
// x: [4,2048,2048] f32 -> M=8192, K=2048 ; W: [8192,2048] f32 -> N=8192
// out: [8192, 8192] f32
//
// GEMM: 256x256 tile, BK=64, 8 waves (2Mx4N), per-wave 128x64, 128KB LDS,
// 32 FAT phases (64 MFMA each) to amortize the ~460cyc/phase fixed overhead
// measured across R5/R7 (barriers+drains+issue). R9 wait discipline:
// every lands-guarantee is an own-wave vmcnt(0) BEFORE a barrier.
// Two-stage lgkm drain hides half the LDS port time under the ks0 MFMAs.
// launch_bounds(512,2) (R9 lesson: (512,4) -> 128-reg cap -> acc spills).

using f16x8 = __attribute__((ext_vector_type(8))) _Float16;
using f32x4 = __attribute__((ext_vector_type(4))) float;

#define AS1 __attribute__((address_space(1)))
#define AS3 __attribute__((address_space(3)))

static __device__ __forceinline__ void gload_lds16(const void* g, void* l) {
    __builtin_amdgcn_global_load_lds((const AS1 void*)g, (AS3 void*)l, 16, 0, 0);
}

// ---------------- weight fake-quant: one block per row ----------------
__global__ __launch_bounds__(256) void wquant_kernel(
    const float* __restrict__ W, const float* __restrict__ lws,
    _Float16* __restrict__ Wq) {
    constexpr int K = 2048;
    const int row = blockIdx.x;
    const int t = threadIdx.x;
    const float* w = W + (size_t)row * K;

    float4 v0 = ((const float4*)w)[t * 2];
    float4 v1 = ((const float4*)w)[t * 2 + 1];
    float vals[8] = {v0.x, v0.y, v0.z, v0.w, v1.x, v1.y, v1.z, v1.w};

    float mn = vals[0], mx = vals[0];
#pragma unroll
    for (int i = 1; i < 8; ++i) {
        mn = fminf(mn, vals[i]);
        mx = fmaxf(mx, vals[i]);
    }
#pragma unroll
    for (int off = 32; off >= 1; off >>= 1) {
        mn = fminf(mn, __shfl_xor(mn, off));
        mx = fmaxf(mx, __shfl_xor(mx, off));
    }
    __shared__ float smn[4], smx[4];
    if ((t & 63) == 0) { smn[t >> 6] = mn; smx[t >> 6] = mx; }
    __syncthreads();
    mn = fminf(fminf(smn[0], smn[1]), fminf(smn[2], smn[3]));
    mx = fmaxf(fmaxf(smx[0], smx[1]), fmaxf(smx[2], smx[3]));

    const float l = lws[row];
    const float ws = exp2f(l);     // power of two -> exact
    const float rs = exp2f(-l);    // exact reciprocal
    const float qwmin = rintf(mn * rs * 2.0f) * 0.5f * ws;
    const float qwmax = rintf(mx * rs * 2.0f) * 0.5f * ws;

    f16x8 out;
#pragma unroll
    for (int i = 0; i < 8; ++i) {
        float c = fminf(fmaxf(vals[i], qwmin), qwmax);
        float qw = rintf((c - qwmin) * rs);
        out[i] = (_Float16)(qw * ws + qwmin);
    }
    *(f16x8*)&Wq[(size_t)row * K + (size_t)t * 8] = out;
}

// ---------------- activation fake-quant: elementwise ----------------
__global__ __launch_bounds__(256) void xquant_kernel(
    const float* __restrict__ X,
    const float* __restrict__ las, const float* __restrict__ laq,
    const float* __restrict__ ab, _Float16* __restrict__ Xq) {
    const float ls = las[0], lq = laq[0];
    const float s = exp2f(ls);
    const float rs = exp2f(-ls);
    const float q = exp2f(lq);
    const float zp = rintf(ab[0] * rs * 2.0f) * 0.5f * s;
    const float lo = zp;
    const float hi = (zp + q) - s;

    const size_t base = ((size_t)blockIdx.x * 256 + threadIdx.x) * 8;
    float4 v0 = *(const float4*)&X[base];
    float4 v1 = *(const float4*)&X[base + 4];
    float vals[8] = {v0.x, v0.y, v0.z, v0.w, v1.x, v1.y, v1.z, v1.w};

    f16x8 out;
#pragma unroll
    for (int i = 0; i < 8; ++i) {
        float c = fminf(fmaxf(vals[i], lo), hi);
        float qx = rintf((c - zp) * rs);
        out[i] = (_Float16)(qx * s + zp);
    }
    *(f16x8*)&Xq[base] = out;
}

// ---------------- GEMM: C[M][N] = A[M][K] * B[N][K]^T + bias ----------------
// LDS: A [db2][half2][128][64] f16 at 0 (64KB), B same at +65536.
// Phase kt (db=kt&1), 32 phases:
//   STAGET(db^1, kt+1)                 8 loads (issued first: max HBM lead)
//   24 ds_read_b128 of tile kt: 12 ks0-grouped, then 12 ks1-grouped
//   lgkm(12) ; sched_barrier ; 32 MFMA(ks0)    <- ks1 reads drain under MFMA
//   lgkm(0)  ; sched_barrier ; 32 MFMA(ks1)
//   VMC(0) ; BAR     (own stage loads drained BEFORE barrier => after the
//                     barrier ALL waves' tile-(kt+1) loads landed)
// WAR: STAGET targets tile kt-1's slots; their readers drained at phase
// kt-1's lgkm(0) before that phase's BAR. Last-iter clamp benign.
__global__ __launch_bounds__(512, 2) void gemm_kernel(
    const _Float16* __restrict__ A, const _Float16* __restrict__ B,
    const float* __restrict__ bias, float* __restrict__ C) {
    constexpr int N = 8192, K = 2048;
    constexpr int KT = K / 64;          // 32 K-tiles = 32 phases
    constexpr int NBN = N / 256;        // 32

    __shared__ char smem[131072];       // A: 0..64K, B: 64K..128K

    // XCD-aware swizzle (nwg = 1024, %8 == 0 -> bijective)
    const int bid = blockIdx.x;
    const int cpx = gridDim.x >> 3;
    const int swzb = (bid & 7) * cpx + (bid >> 3);
    const int bm = swzb / NBN;
    const int bn = swzb % NBN;

    const int t = threadIdx.x;
    const int lane = t & 63;
    const int wid = t >> 6;
    const int wr = wid >> 2;            // 0..1 (M half)
    const int wc = wid & 3;             // 0..3 (N quarter)
    const int l15 = lane & 15;
    const int lq = lane >> 4;

    // staging: half-tile [128 rows][64 k] f16 = 16384 B, linear LDS dest,
    // pre-swizzled global source. T2: byte ^= (row&7)<<4 (R5-verified, 0 cf).
    const int d0 = t * 16, d1 = d0 + 8192;
    const int r0 = d0 >> 7, c0 = (((d0 & 127) ^ (((d0 >> 7) & 7) << 4)) >> 1);
    const int r1 = d1 >> 7, c1 = (((d1 & 127) ^ (((d1 >> 7) & 7) << 4)) >> 1);
    const _Float16* Agb = A + (size_t)bm * 256 * K;
    const _Float16* Bgb = B + (size_t)bn * 256 * K;

    // read-side swizzled k-col byte offsets (frag row&7 == l15&7)
    const int cp0 = (lq * 16) ^ ((l15 & 7) << 4);
    const int cp1 = cp0 ^ 64;           // second K-half (bit6 XOR)

    f32x4 acc[8][4] = {};
    f16x8 fA[8][2], fB[4][2];

#define STAGEH(GB, RO, DBS, H, KS) do {                                        \
        const _Float16* _g = (GB) + (size_t)((H) * 128) * K + (size_t)(KS) * 64;\
        char* _l = smem + (RO) + ((DBS) * 2 + (H)) * 16384;                    \
        gload_lds16(_g + (size_t)r0 * K + c0, _l + d0);                        \
        gload_lds16(_g + (size_t)r1 * K + c1, _l + d1);                        \
    } while (0)

#define STAGET(DBS, KS) do {                                                   \
        STAGEH(Agb, 0,     DBS, 0, KS);                                        \
        STAGEH(Agb, 0,     DBS, 1, KS);                                        \
        STAGEH(Bgb, 65536, DBS, 0, KS);                                        \
        STAGEH(Bgb, 65536, DBS, 1, KS);                                        \
    } while (0)

#define VMC(NN) asm volatile("s_waitcnt vmcnt(" #NN ")" ::: "memory")
#define BAR()   __builtin_amdgcn_s_barrier()
#define PRIO(P) __builtin_amdgcn_s_setprio(P)

    // ---- prologue: stage tile 0 into db0; drain BEFORE barrier ----
    STAGET(0, 0);
    VMC(0);
    BAR();

    for (int kt = 0; kt < KT; ++kt) {
        const int db = kt & 1;
        const int nx = (kt + 1 < KT) ? kt + 1 : KT - 1;

        STAGET(db ^ 1, nx);              // 8 loads for tile kt+1

        // 24 ds_read_b128 of tile kt, grouped by k-slice
        const char* _a = smem + (db * 2 + wr) * 16384 + l15 * 128;
        const char* _b = smem + 65536 + (db * 2 + (wc >> 1)) * 16384 +
                         (wc & 1) * 8192 + l15 * 128;
#pragma unroll
        for (int m = 0; m < 8; ++m)
            fA[m][0] = *(const f16x8*)(_a + m * 2048 + cp0);
#pragma unroll
        for (int n = 0; n < 4; ++n)
            fB[n][0] = *(const f16x8*)(_b + n * 2048 + cp0);
#pragma unroll
        for (int m = 0; m < 8; ++m)
            fA[m][1] = *(const f16x8*)(_a + m * 2048 + cp1);
#pragma unroll
        for (int n = 0; n < 4; ++n)
            fB[n][1] = *(const f16x8*)(_b + n * 2048 + cp1);

        // ks0 cluster: wait only for the first 12 reads
        asm volatile("s_waitcnt lgkmcnt(12)" ::: "memory");
        __builtin_amdgcn_sched_barrier(0);
        PRIO(1);
#pragma unroll
        for (int m = 0; m < 8; ++m)
#pragma unroll
            for (int n = 0; n < 4; ++n)
                acc[m][n] = __builtin_amdgcn_mfma_f32_16x16x32_f16(
                    fA[m][0], fB[n][0], acc[m][n], 0, 0, 0);
        PRIO(0);

        // ks1 cluster
        asm volatile("s_waitcnt lgkmcnt(0)" ::: "memory");
        __builtin_amdgcn_sched_barrier(0);
        PRIO(1);
#pragma unroll
        for (int m = 0; m < 8; ++m)
#pragma unroll
            for (int n = 0; n < 4; ++n)
                acc[m][n] = __builtin_amdgcn_mfma_f32_16x16x32_f16(
                    fA[m][1], fB[n][1], acc[m][n], 0, 0, 0);
        PRIO(0);

        VMC(0);                          // own stage loads drained
        BAR();                           // => all waves' loads landed
    }
#undef STAGEH
#undef STAGET
#undef VMC
#undef BAR
#undef PRIO

    // ---- epilogue: C/D mapping col=lane&15, row=(lane>>4)*4+reg ----
#pragma unroll
    for (int m = 0; m < 8; ++m) {
        const int row = bm * 256 + wr * 128 + m * 16 + lq * 4;
#pragma unroll
        for (int n = 0; n < 4; ++n) {
            const int col = bn * 256 + wc * 64 + n * 16 + l15;
            const float bv = bias[col];
#pragma unroll
            for (int r = 0; r < 4; ++r) {
                C[(size_t)(row + r) * N + col] = acc[m][n][r] + bv;
            }
        }
    }
}

extern "C" void kernel_launch(void* const* d_in, const int* in_sizes, int n_in,
                              void* d_out, int out_size, void* d_ws, size_t ws_size,
                              hipStream_t stream) {
    const float* x    = (const float*)d_in[0];   // [4,2048,2048]
    const float* w    = (const float*)d_in[1];   // [8192,2048]
    const float* bias = (const float*)d_in[2];   // [8192]
    const float* las  = (const float*)d_in[3];   // log_act_s [1]
    const float* laq  = (const float*)d_in[4];   // log_act_q [1]
    const float* ab   = (const float*)d_in[5];   // act_b [1]
    const float* lws  = (const float*)d_in[6];   // log_wght_s [8192]
    float* out = (float*)d_out;

    constexpr size_t MK = (size_t)8192 * 2048;
    _Float16* xq = (_Float16*)d_ws;
    _Float16* wq = (_Float16*)((char*)d_ws + MK * sizeof(_Float16));

    xquant_kernel<<<8192, 256, 0, stream>>>(x, las, laq, ab, xq);
    wquant_kernel<<<8192, 256, 0, stream>>>(w, lws, wq);
    gemm_kernel<<<1024, 512, 0, stream>>>(xq, wq, bias, out);
}